// Round 10
// baseline (393.221 us; speedup 1.0000x reference)
//
#include <hip/hip_runtime.h>

typedef unsigned short u16;
typedef unsigned int u32;
typedef __attribute__((ext_vector_type(8))) short bf16x8;
typedef __attribute__((ext_vector_type(4))) float f32x4;

#define MFMA(a, b, c) __builtin_amdgcn_mfma_f32_16x16x32_bf16(a, b, c, 0, 0, 0)

__device__ __forceinline__ float b2f(u32 lo16) {
  union { u32 i; float f; } v; v.i = lo16 << 16; return v.f;
}
__device__ __forceinline__ u16 f2b(float f) {  // RNE scalar
  union { float f; u32 i; } v; v.f = f;
  return (u16)((v.i + 0x7fffu + ((v.i >> 16) & 1u)) >> 16);
}
__device__ __forceinline__ u32 pk2(float a, float b) {  // 2xf32 -> packed bf16 RNE
  u32 r; asm("v_cvt_pk_bf16_f32 %0, %1, %2" : "=v"(r) : "v"(a), "v"(b)); return r;
}
__device__ __forceinline__ bf16x8 ld8(const u16* p) { return *(const bf16x8*)p; }

// Padded activation geometry:
//  h2p, qp : [32][66][66][64] bf16 (1-px zero border)
//  d1p     : [32][132][144][64] bf16 (row 0 & 129..131, col 0 & 129..143 zero)

// ---------------------------------------------------------------------------
// prep: pack weights to MFMA frag order ([l][8], 16dim=l&15, k=8*(l>>4)+j),
// cnorm, zero loss, zero h2p/qp borders.
// ---------------------------------------------------------------------------
__global__ void prep_k(const float* __restrict__ ew1, const float* __restrict__ ew2,
                       const float* __restrict__ ew3, const float* __restrict__ dw1,
                       const float* __restrict__ dw2, const float* __restrict__ dw3,
                       const float* __restrict__ cb,
                       float* W1, u16* Bp2, u16* Bp3, u16* BpT1, u16* BpT2,
                       u16* Bpd3, u16* Bpvq, float* cnorm, float* loss,
                       u16* h2p, u16* qp) {
  int tid = blockIdx.x * blockDim.x + threadIdx.x;
  int nth = gridDim.x * blockDim.x;
  for (int i = tid; i < 1536; i += nth) {
    int oc = i & 31; int r = i >> 5; int kw = r & 3; r >>= 2; int kh = r & 3; int ic = r >> 2;
    W1[i] = ew1[((oc*3 + ic)*4 + kh)*4 + kw];
  }
  for (int i = tid; i < 32768; i += nth) {  // Bp2[t16][nt4][l][8]
    int j = i & 7, li = (i >> 3) & 63, nt = (i >> 9) & 3, t = i >> 11;
    int ic = 8*(li >> 4) + j, oc = 16*nt + (li & 15), kh = t >> 2, kw = t & 3;
    Bp2[i] = f2b(ew2[((oc*32 + ic)*4 + kh)*4 + kw]);
  }
  for (int i = tid; i < 36864; i += nth) {  // Bp3[t9][kc2][nt4][l][8]
    int j = i & 7, li = (i >> 3) & 63, nt = (i >> 9) & 3, kc = (i >> 11) & 1, t = i >> 12;
    int ic = 32*kc + 8*(li >> 4) + j, oc = 16*nt + (li & 15), kh = t / 3, kw = t % 3;
    Bp3[i] = f2b(ew3[((oc*64 + ic)*3 + kh)*3 + kw]);
  }
  for (int i = tid; i < 65536; i += nth) {  // BpT1[p4][t4][kc2][nt4][l][8]
    int j = i & 7, li = (i >> 3) & 63, nt = (i >> 9) & 3, kc = (i >> 11) & 1,
        t = (i >> 12) & 3, p = i >> 14;
    int a = p >> 1, b = p & 1;
    int ky = (1 - a) + 2*(t >> 1), kx = (1 - b) + 2*(t & 1);
    int ic = 32*kc + 8*(li >> 4) + j, oc = 16*nt + (li & 15);
    BpT1[i] = f2b(dw1[((ic*64 + oc)*4 + ky)*4 + kx]);
  }
  for (int i = tid; i < 32768; i += nth) {  // BpT2[p4][t4][kc2][mt2][l][8]
    int j = i & 7, li = (i >> 3) & 63, mt = (i >> 9) & 1, kc = (i >> 10) & 1,
        t = (i >> 11) & 3, p = i >> 13;
    int a = p >> 1, b = p & 1;
    int ky = (1 - a) + 2*(t >> 1), kx = (1 - b) + 2*(t & 1);
    int oc = 16*mt + (li & 15);
    int ic = 32*kc + 8*(li >> 4) + j;
    BpT2[i] = f2b(dw2[((ic*32 + oc)*4 + ky)*4 + kx]);
  }
  for (int i = tid; i < 4608; i += nth) {  // Bpd3[t9][l][8], n pad 16
    int j = i & 7, li = (i >> 3) & 63, t = i >> 9;
    int n = li & 15, ic = 8*(li >> 4) + j, kh = t / 3, kw = t % 3;
    Bpd3[i] = (n < 3) ? f2b(dw3[((n*32 + ic)*3 + kh)*3 + kw]) : (u16)0;
  }
  for (int i = tid; i < 32768; i += nth) {  // Bpvq[kc2][nt32][l][8]
    int j = i & 7, li = (i >> 3) & 63, nt = (i >> 9) & 31, kc = i >> 14;
    int d = 32*kc + 8*(li >> 4) + j, code = 16*nt + (li & 15);
    Bpvq[i] = f2b(cb[code*64 + d]);
  }
  for (int k = tid; k < 512; k += nth) {
    float s = 0.f;
    for (int d = 0; d < 64; ++d) { float c = cb[k*64 + d]; s += c*c; }
    cnorm[k] = s;
  }
  // zero h2p & qp borders (260 border cells per 66x66 image)
  for (int i = tid; i < 32*260; i += nth) {
    int im = i / 260, c = i % 260;
    int y, x;
    if (c < 66) { y = 0; x = c; }
    else if (c < 132) { y = 65; x = c - 66; }
    else if (c < 196) { y = c - 131; x = 0; }
    else { y = c - 195; x = 65; }
    size_t off = ((size_t)(im*66 + y)*66 + x)*64;
    uint4 zv = {0,0,0,0};
    uint4* p1 = (uint4*)(h2p + off); uint4* p2 = (uint4*)(qp + off);
#pragma unroll
    for (int j = 0; j < 8; ++j) { p1[j] = zv; p2[j] = zv; }
  }
  if (tid == 0) *loss = 0.f;
}

// zero d1p borders (2624 border cells per 132x144 image). Runs after vqm.
__global__ void zpad_k(u16* __restrict__ d1p) {
  int i = blockIdx.x*256 + threadIdx.x;
  if (i >= 32*2624) return;
  int im = i / 2624, c = i % 2624;
  int row, col;
  if (c < 576) { int rr = c / 144; row = (rr == 0) ? 0 : 128 + rr; col = c % 144; }
  else { int c2 = c - 576; row = c2 / 16 + 1; int k = c2 & 15; col = k ? 128 + k : 0; }
  uint4* p = (uint4*)(d1p + ((size_t)(im*132 + row)*144 + col)*64);
  uint4 zv = {0,0,0,0};
#pragma unroll
  for (int j = 0; j < 8; ++j) p[j] = zv;
}

// ---------------------------------------------------------------------------
// conv1 (VALU): x f32 NCHW -> h1 bf16 NHWC[32][128][128][32] (unpadded)
// ---------------------------------------------------------------------------
__global__ __launch_bounds__(256) void conv1_k(
    const float* __restrict__ x, const float* __restrict__ W1,
    const float* __restrict__ b1, u16* __restrict__ h1) {
  __shared__ float ins[3*18*36];
  int Tx = blockIdx.x, Ty = blockIdx.y, b = blockIdx.z;
  int tid = threadIdx.x;
  for (int i = tid; i < 3*18*36; i += 256) {
    int c = i % 36; int r = (i / 36) % 18; int ic = i / 648;
    int iy = 16*Ty - 1 + r, ix = 32*Tx - 2 + c;
    float v = 0.f;
    if ((unsigned)iy < 256u && (unsigned)ix < 256u)
      v = x[((size_t)(b*3 + ic)*256 + iy)*256 + ix];
    ins[i] = v;
  }
  __syncthreads();
  int posg = tid & 31, ocg = tid >> 5;
  int Y = posg >> 2, Xg = posg & 3;
  int oc0 = ocg * 4;
  float acc[4][4];
#pragma unroll
  for (int j = 0; j < 4; ++j) { float bv = b1[oc0 + j];
#pragma unroll
    for (int e = 0; e < 4; ++e) acc[j][e] = bv; }
  for (int ic = 0; ic < 3; ++ic)
#pragma unroll
    for (int kh = 0; kh < 4; ++kh) {
      const float* row = &ins[ic*648 + (2*Y + kh)*36 + 8*Xg];
      float win[12];
#pragma unroll
      for (int t = 0; t < 12; ++t) win[t] = row[t];
#pragma unroll
      for (int kw = 0; kw < 4; ++kw) {
        const float* wp = &W1[((ic*4 + kh)*4 + kw)*32 + oc0];
        float w0 = wp[0], w1 = wp[1], w2 = wp[2], w3 = wp[3];
#pragma unroll
        for (int e = 0; e < 4; ++e) {
          float v = win[2*e + kw + 1];
          acc[0][e] += w0*v; acc[1][e] += w1*v; acc[2][e] += w2*v; acc[3][e] += w3*v;
        }
      }
    }
  int oy = 8*Ty + Y;
  int oxb = 16*Tx + 4*Xg;
#pragma unroll
  for (int e = 0; e < 4; ++e) {
    u32 lo = pk2(fmaxf(acc[0][e], 0.f), fmaxf(acc[1][e], 0.f));
    u32 hi = pk2(fmaxf(acc[2][e], 0.f), fmaxf(acc[3][e], 0.f));
    *(uint2*)&h1[((size_t)(b*128 + oy)*128 + oxb + e)*32 + oc0] = (uint2){lo, hi};
  }
}

// ---------------------------------------------------------------------------
// conv2 (MFMA, A=weights): h1 -> h2p (padded NHWC), k4 s2 p1 relu.
// ---------------------------------------------------------------------------
__global__ __launch_bounds__(256) void conv2_k(
    const u16* __restrict__ h1, const u16* __restrict__ Bp2,
    const float* __restrict__ eb2, u16* __restrict__ h2p) {
  __shared__ u16 lds[2448*8];  // [row18][c4][x34][8]
  int Tx = blockIdx.x, Ty = blockIdx.y, img = blockIdx.z;
  int tid = threadIdx.x;
  for (int i = tid; i < 2448; i += 256) {
    int c = i & 3; int x = (i >> 2) % 34; int row = (i >> 2) / 34;
    int iy = 16*Ty - 1 + row, ix = 32*Tx - 1 + x;
    f32x4 v = {0,0,0,0};
    if ((unsigned)iy < 128u && (unsigned)ix < 128u)
      v = *(const f32x4*)(h1 + (((size_t)(img*128 + iy)*128 + ix)*32 + c*8));
    *(f32x4*)(lds + ((row*4 + c)*34 + x)*8) = v;
  }
  __syncthreads();
  int w = tid >> 6, l = tid & 63, lg = l >> 4, lc = l & 15;
  f32x4 acc[2][4];
#pragma unroll
  for (int mt = 0; mt < 4; ++mt) {
    f32x4 bv = *(const f32x4*)(eb2 + mt*16 + 4*lg);
    acc[0][mt] = bv; acc[1][mt] = bv;
  }
#pragma unroll
  for (int t = 0; t < 16; ++t) {
    int kh = t >> 2, kw = t & 3;
    bf16x8 a0 = ld8(lds + (((2*w + kh)*4 + lg)*34 + 2*lc + kw)*8);
    bf16x8 a1 = ld8(lds + (((2*(w+4) + kh)*4 + lg)*34 + 2*lc + kw)*8);
    const u16* bp = Bp2 + t*2048 + l*8;
    bf16x8 w0 = ld8(bp), w1 = ld8(bp + 512), w2 = ld8(bp + 1024), w3 = ld8(bp + 1536);
    acc[0][0] = MFMA(w0, a0, acc[0][0]); acc[0][1] = MFMA(w1, a0, acc[0][1]);
    acc[0][2] = MFMA(w2, a0, acc[0][2]); acc[0][3] = MFMA(w3, a0, acc[0][3]);
    acc[1][0] = MFMA(w0, a1, acc[1][0]); acc[1][1] = MFMA(w1, a1, acc[1][1]);
    acc[1][2] = MFMA(w2, a1, acc[1][2]); acc[1][3] = MFMA(w3, a1, acc[1][3]);
  }
#pragma unroll
  for (int m = 0; m < 2; ++m) {
    int oy = 8*Ty + w + m*4;
    u16* base = h2p + (((size_t)img*66 + oy + 1)*66 + 16*Tx + lc + 1)*64 + 4*lg;
#pragma unroll
    for (int mt = 0; mt < 4; ++mt) {
      f32x4 v = acc[m][mt];
      u32 lo = pk2(fmaxf(v[0], 0.f), fmaxf(v[1], 0.f));
      u32 hi = pk2(fmaxf(v[2], 0.f), fmaxf(v[3], 0.f));
      *(uint2*)(base + mt*16) = (uint2){lo, hi};
    }
  }
}

// ---------------------------------------------------------------------------
// conv3 enc (MFMA, A=weights, direct-L2 reads from padded h2p): -> z (unpadded)
// ---------------------------------------------------------------------------
__global__ __launch_bounds__(256) void conv3e_k(
    const u16* __restrict__ h2p, const u16* __restrict__ Bp3,
    const float* __restrict__ eb3, u16* __restrict__ z) {
  int Tx = blockIdx.x, Ty = blockIdx.y, img = blockIdx.z;
  int tid = threadIdx.x;
  int w = tid >> 6, l = tid & 63, lg = l >> 4, lc = l & 15;
  const u16* hbase = h2p + (size_t)img * (66*66*64);
  int row0 = 8*Ty + w;
  int col = 16*Tx + lc;
  f32x4 acc[2][4];
#pragma unroll
  for (int mt = 0; mt < 4; ++mt) {
    f32x4 bv = *(const f32x4*)(eb3 + mt*16 + 4*lg);
    acc[0][mt] = bv; acc[1][mt] = bv;
  }
#pragma unroll
  for (int t = 0; t < 9; ++t) {
    int kh = t / 3, kw = t % 3;
#pragma unroll
    for (int kc = 0; kc < 2; ++kc) {
      bf16x8 a0 = ld8(hbase + ((size_t)(row0 + kh)*66 + col + kw)*64 + kc*32 + lg*8);
      bf16x8 a1 = ld8(hbase + ((size_t)(row0 + 4 + kh)*66 + col + kw)*64 + kc*32 + lg*8);
      const u16* bp = Bp3 + (t*2 + kc)*2048 + l*8;
      bf16x8 w0 = ld8(bp), w1 = ld8(bp + 512), w2 = ld8(bp + 1024), w3 = ld8(bp + 1536);
      acc[0][0] = MFMA(w0, a0, acc[0][0]); acc[0][1] = MFMA(w1, a0, acc[0][1]);
      acc[0][2] = MFMA(w2, a0, acc[0][2]); acc[0][3] = MFMA(w3, a0, acc[0][3]);
      acc[1][0] = MFMA(w0, a1, acc[1][0]); acc[1][1] = MFMA(w1, a1, acc[1][1]);
      acc[1][2] = MFMA(w2, a1, acc[1][2]); acc[1][3] = MFMA(w3, a1, acc[1][3]);
    }
  }
#pragma unroll
  for (int m = 0; m < 2; ++m) {
    int oy = 8*Ty + w + m*4;
    u16* base = z + ((size_t)(img*64 + oy)*64 + 16*Tx + lc)*64 + 4*lg;
#pragma unroll
    for (int mt = 0; mt < 4; ++mt) {
      f32x4 v = acc[m][mt];
      *(uint2*)(base + mt*16) = (uint2){pk2(v[0], v[1]), pk2(v[2], v[3])};
    }
  }
}

// ---------------------------------------------------------------------------
// VQ (MFMA): z -> qp (padded) + loss. 1024 blocks x 2 iters.
// ---------------------------------------------------------------------------
__global__ __launch_bounds__(256) void vqm_k(
    const u16* __restrict__ z, const u16* __restrict__ Bpvq,
    const float* __restrict__ cnorm, const float* __restrict__ cbf,
    u16* __restrict__ qp, float* __restrict__ loss) {
  __shared__ u16 cbl[32768];
  __shared__ float cnl[512];
  __shared__ int idxl[64];
  __shared__ float red[256];
  int tid = threadIdx.x;
  for (int i = tid; i < 4096; i += 256)
    *(f32x4*)(cbl + i*8) = *(const f32x4*)(Bpvq + i*8);
  for (int i = tid; i < 512; i += 256) cnl[i] = cnorm[i];
  __syncthreads();
  int w = tid >> 6, l = tid & 63, lg = l >> 4, lc = l & 15;
  int wglobal = blockIdx.x*4 + w;
  float lsum = 0.f;
  for (int it = 0; it < 2; ++it) {
    int mf = wglobal + it*4096;
    size_t P = (size_t)mf * 16;
    bf16x8 a0 = ld8(z + (P + lc)*64 + lg*8);
    bf16x8 a1 = ld8(z + (P + lc)*64 + 32 + lg*8);
    float best[4] = {1e30f, 1e30f, 1e30f, 1e30f};
    int bidx[4] = {0, 0, 0, 0};
    for (int nt = 0; nt < 32; ++nt) {
      f32x4 acc = {0,0,0,0};
      acc = MFMA(a0, ld8(cbl + (nt*64 + l)*8), acc);
      acc = MFMA(a1, ld8(cbl + ((32 + nt)*64 + l)*8), acc);
      float cn = cnl[nt*16 + lc];
      int code = nt*16 + lc;
#pragma unroll
      for (int r = 0; r < 4; ++r) {
        float dist = cn - 2.f*acc[r];
        if (dist < best[r]) { best[r] = dist; bidx[r] = code; }
      }
    }
#pragma unroll
    for (int r = 0; r < 4; ++r) {
      float b = best[r]; int bi = bidx[r];
      for (int m = 1; m < 16; m <<= 1) {
        float ob = __shfl_xor(b, m);
        int oi = __shfl_xor(bi, m);
        if (ob < b || (ob == b && oi < bi)) { b = ob; bi = oi; }
      }
      if (lc == 0) idxl[w*16 + lg*4 + r] = bi;
    }
    int m = lc, ch0 = lg*16;
    int id = idxl[w*16 + m];
    const float* crow = cbf + (size_t)id*64 + ch0;
    const u16* zp = z + (P + m)*64 + ch0;
    int n = (int)P + m;
    int im2 = n >> 12, hw2 = n & 4095, yy2 = hw2 >> 6, xx2 = hw2 & 63;
    u32* qpw = (u32*)(qp + ((size_t)(im2*66 + yy2 + 1)*66 + xx2 + 1)*64 + ch0);
#pragma unroll
    for (int c = 0; c < 16; c += 2) {
      float c0 = crow[c], c1 = crow[c+1];
      float d0 = c0 - b2f(zp[c]), d1 = c1 - b2f(zp[c+1]);
      lsum += d0*d0 + d1*d1;
      qpw[c >> 1] = pk2(c0, c1);
    }
  }
  red[tid] = lsum;
  __syncthreads();
  for (int s = 128; s > 0; s >>= 1) {
    if (tid < s) red[tid] += red[tid + s];
    __syncthreads();
  }
  if (tid == 0) atomicAdd(loss, red[0] * (1.25f / 8388608.f));
}

// ---------------------------------------------------------------------------
// convT1 (MFMA, A=weights, parity, direct-L2 reads from padded qp):
// -> d1p (padded NHWC), k4 s2 p1 relu. No LDS, no masks.
// ---------------------------------------------------------------------------
__global__ __launch_bounds__(256) void convt1_k(
    const u16* __restrict__ qp, const u16* __restrict__ BpT1,
    const float* __restrict__ db1, u16* __restrict__ d1p) {
  int Tx = blockIdx.x, Ty = blockIdx.y, img = blockIdx.z;
  int X0 = 16*Tx, P0 = 4*Ty;
  int tid = threadIdx.x;
  int w = tid >> 6, l = tid & 63, lg = l >> 4, lc = l & 15;
  int a = w & 1, bp_ = w >> 1;
  const u16* qbase = qp + (size_t)img * (66*66*64);
  f32x4 acc[4][4];
#pragma unroll
  for (int mt = 0; mt < 4; ++mt) {
    f32x4 bv = *(const f32x4*)(db1 + mt*16 + 4*lg);
#pragma unroll
    for (int m = 0; m < 4; ++m) acc[m][mt] = bv;
  }
  const u16* bbase = BpT1 + (size_t)(a*2 + bp_)*16384;
#pragma unroll
  for (int kxi = 0; kxi < 2; ++kxi) {
    int colp = X0 + 1 + lc + bp_ - kxi;
#pragma unroll
    for (int kc = 0; kc < 2; ++kc) {
      bf16x8 av[5];
#pragma unroll
      for (int rr = 0; rr < 5; ++rr)
        av[rr] = ld8(qbase + ((size_t)(P0 + rr)*66 + colp)*64 + kc*32 + lg*8);
#pragma unroll
      for (int kyi = 0; kyi < 2; ++kyi) {
        int t = kyi*2 + kxi;
        const u16* bp = bbase + (t*2 + kc)*2048 + l*8;
        bf16x8 w0 = ld8(bp), w1 = ld8(bp + 512), w2 = ld8(bp + 1024), w3 = ld8(bp + 1536);
#pragma unroll
        for (int m = 0; m < 4; ++m) {
          bf16x8 dv = av[m + 1 - kyi];
          acc[m][0] = MFMA(w0, dv, acc[m][0]);
          acc[m][1] = MFMA(w1, dv, acc[m][1]);
          acc[m][2] = MFMA(w2, dv, acc[m][2]);
          acc[m][3] = MFMA(w3, dv, acc[m][3]);
        }
      }
    }
  }
  int ox = 2*(X0 + lc) + bp_;
#pragma unroll
  for (int m = 0; m < 4; ++m) {
    int oy = 2*(P0 + m) + a;
    u16* base = d1p + ((size_t)(img*132 + oy + 1)*144 + ox + 1)*64 + 4*lg;
#pragma unroll
    for (int mt = 0; mt < 4; ++mt) {
      f32x4 v = acc[m][mt];
      u32 lo = pk2(fmaxf(v[0], 0.f), fmaxf(v[1], 0.f));
      u32 hi = pk2(fmaxf(v[2], 0.f), fmaxf(v[3], 0.f));
      *(uint2*)(base + mt*16) = (uint2){lo, hi};
    }
  }
}

// ---------------------------------------------------------------------------
// tail (MFMA): fused convT2+relu+conv3+sigmoid. Phase 1 reads padded d1p
// directly (no staging, no masks); d2q in LDS (20.5 KB -> 7 blocks/CU);
// one barrier. Edge masks only for out-of-image d2 zeroing + output stores.
// ---------------------------------------------------------------------------
__global__ __launch_bounds__(256) void tail_k(
    const u16* __restrict__ d1p, const u16* __restrict__ BpT2,
    const float* __restrict__ db2, const u16* __restrict__ Bpd3,
    const float* __restrict__ db3, float* __restrict__ out) {
  __shared__ u16 d2q[10240];    // [quad4][m4][x16][40]
  int Tx = blockIdx.x, Ty = blockIdx.y, img = blockIdx.z;
  int DX0 = 30*Tx - 1, DY0 = 6*Ty - 1;   // both odd
  int IYB = 3*Ty, IXB = 15*Tx;
  int tid = threadIdx.x;
  bool edge = (Tx == 0) | (Tx == 8) | (Ty == 0) | (Ty == 42);
  int w = tid >> 6, l = tid & 63, lg = l >> 4, lc = l & 15;
  const u16* dbase = d1p + (size_t)img * (132*144*64);
  {
    int a = w & 1, b = w >> 1;
    f32x4 acc[4][2];
#pragma unroll
    for (int mt = 0; mt < 2; ++mt) {
      f32x4 bv = *(const f32x4*)(db2 + 16*mt + 4*lg);
#pragma unroll
      for (int m = 0; m < 4; ++m) acc[m][mt] = bv;
    }
    const u16* bbase = BpT2 + (size_t)(a*2 + b)*8192;
#pragma unroll
    for (int kxi = 0; kxi < 2; ++kxi) {
      int colp = IXB + lc - kxi + 1;   // padded col, in [0,137]
#pragma unroll
      for (int kc = 0; kc < 2; ++kc) {
        bf16x8 av[5];
#pragma unroll
        for (int rr = 0; rr < 5; ++rr)
          av[rr] = ld8(dbase + ((size_t)(IYB + rr)*144 + colp)*64 + kc*32 + lg*8);
#pragma unroll
        for (int kyi = 0; kyi < 2; ++kyi) {
          int t = kyi*2 + kxi;
          const u16* wb = bbase + (t*2 + kc)*1024 + l*8;
          bf16x8 w0 = ld8(wb), w1 = ld8(wb + 512);
#pragma unroll
          for (int m = 0; m < 4; ++m) {
            acc[m][0] = MFMA(w0, av[m + 1 - kyi], acc[m][0]);
            acc[m][1] = MFMA(w1, av[m + 1 - kyi], acc[m][1]);
          }
        }
      }
    }
    int base = (a*2 + b)*2560 + lc*40 + 4*lg;   // u16 units; + m*640 + mt*16
    if (!edge) {
#pragma unroll
      for (int m = 0; m < 4; ++m)
#pragma unroll
        for (int mt = 0; mt < 2; ++mt) {
          f32x4 v = acc[m][mt];
          u32 lo = pk2(fmaxf(v[0], 0.f), fmaxf(v[1], 0.f));
          u32 hi = pk2(fmaxf(v[2], 0.f), fmaxf(v[3], 0.f));
          *(uint2*)(d2q + base + m*640 + mt*16) = (uint2){lo, hi};
        }
    } else {
      int oxc = b ? DX0 : DX0 + 1;
      bool cm = (unsigned)(oxc + 2*lc) < 256u;
      int oyc = a ? DY0 : DY0 + 1;
#pragma unroll
      for (int m = 0; m < 4; ++m) {
        bool ok = ((unsigned)(oyc + 2*m) < 256u) && cm;
#pragma unroll
        for (int mt = 0; mt < 2; ++mt) {
          f32x4 v = acc[m][mt];
          u32 lo = 0, hi = 0;
          if (ok) {
            lo = pk2(fmaxf(v[0], 0.f), fmaxf(v[1], 0.f));
            hi = pk2(fmaxf(v[2], 0.f), fmaxf(v[3], 0.f));
          }
          *(uint2*)(d2q + base + m*640 + mt*16) = (uint2){lo, hi};
        }
      }
    }
  }
  __syncthreads();
  bf16x8 bw[9];
#pragma unroll
  for (int t = 0; t < 9; ++t) bw[t] = ld8(Bpd3 + t*512 + l*8);
  float bv3 = (lc < 3) ? db3[lc] : 0.f;
#pragma unroll
  for (int i = 0; i < 3; ++i) {
    int u = w + 4*i;                 // 12 units, 3 per wave
    int yy = u >> 1, xf = u & 1;
    int gy = DY0 + 1 + yy;
    int cOff[3];
#pragma unroll
    for (int kw = 0; kw < 3; ++kw) {
      int lx = xf*16 + lc + kw; if (lx > 31) lx = 31;
      cOff[kw] = (1 - (lx & 1))*2560 + (lx >> 1)*40 + 8*lg;
    }
    f32x4 acc = {bv3, bv3, bv3, bv3};
#pragma unroll
    for (int kh = 0; kh < 3; ++kh) {
      int ly = yy + kh;
      int rOff = (1 - (ly & 1))*5120 + (ly >> 1)*640;
#pragma unroll
      for (int kw = 0; kw < 3; ++kw)
        acc = MFMA(ld8(d2q + rOff + cOff[kw]), bw[kh*3 + kw], acc);
    }
    if (lc < 3) {
      if (!edge) {
#pragma unroll
        for (int r = 0; r < 4; ++r) {
          int xi = xf*16 + 4*lg + r;
          if (xi < 30)
            out[((size_t)(img*3 + lc)*256 + gy)*256 + DX0 + 1 + xi] =
                __builtin_amdgcn_rcpf(1.f + __expf(-acc[r]));
        }
      } else if ((unsigned)gy < 256u) {
#pragma unroll
        for (int r = 0; r < 4; ++r) {
          int xi = xf*16 + 4*lg + r;
          int gx = DX0 + 1 + xi;
          if (xi < 30 && (unsigned)gx < 256u)
            out[((size_t)(img*3 + lc)*256 + gy)*256 + gx] =
                __builtin_amdgcn_rcpf(1.f + __expf(-acc[r]));
        }
      }
    }
  }
}

extern "C" void kernel_launch(void* const* d_in, const int* in_sizes, int n_in,
                              void* d_out, int out_size, void* d_ws, size_t ws_size,
                              hipStream_t stream) {
  const float* x   = (const float*)d_in[0];
  const float* ew1 = (const float*)d_in[1];
  const float* eb1 = (const float*)d_in[2];
  const float* ew2 = (const float*)d_in[3];
  const float* eb2 = (const float*)d_in[4];
  const float* ew3 = (const float*)d_in[5];
  const float* eb3 = (const float*)d_in[6];
  const float* cb  = (const float*)d_in[7];
  const float* dw1 = (const float*)d_in[8];
  const float* db1 = (const float*)d_in[9];
  const float* dw2 = (const float*)d_in[10];
  const float* db2 = (const float*)d_in[11];
  const float* dw3 = (const float*)d_in[12];
  const float* db3 = (const float*)d_in[13];
  float* out = (float*)d_out;

  // ws layout (liveness-checked, peak ~97 MiB):
  //   d1p [0, 74.3M)  — with z [0,16M), h2p [17M,34.1M), h1 [35M,67M) nested
  //   (all dead before convt1 writes d1p); qp [78M, 95.1M); weights @96M.
  char* ws = (char*)d_ws;
  const size_t MB = 1048576;
  u16* d1p = (u16*)ws;
  u16* z   = (u16*)ws;
  u16* h2p = (u16*)(ws + 17*MB);
  u16* h1  = (u16*)(ws + 35*MB);
  u16* qp  = (u16*)(ws + 78*MB);
  char* wp = ws + 96*MB;
  float* W1   = (float*)wp;  wp += 6144;
  u16*  Bp2   = (u16*)wp;    wp += 65536;
  u16*  Bp3   = (u16*)wp;    wp += 73728;
  u16*  BpT1  = (u16*)wp;    wp += 131072;
  u16*  BpT2  = (u16*)wp;    wp += 65536;
  u16*  Bpd3  = (u16*)wp;    wp += 9216;
  u16*  Bpvq  = (u16*)wp;    wp += 65536;
  float* cnorm = (float*)wp; wp += 2048;
  float* loss = out + 6291456;

  prep_k<<<64, 256, 0, stream>>>(ew1, ew2, ew3, dw1, dw2, dw3, cb,
                                 W1, Bp2, Bp3, BpT1, BpT2, Bpd3, Bpvq, cnorm, loss,
                                 h2p, qp);
  conv1_k<<<dim3(8, 16, 32), 256, 0, stream>>>(x, W1, eb1, h1);
  conv2_k<<<dim3(4, 8, 32), 256, 0, stream>>>(h1, Bp2, eb2, h2p);
  conv3e_k<<<dim3(4, 8, 32), 256, 0, stream>>>(h2p, Bp3, eb3, z);
  vqm_k<<<1024, 256, 0, stream>>>(z, Bpvq, cnorm, cb, qp, loss);
  zpad_k<<<328, 256, 0, stream>>>(d1p);
  convt1_k<<<dim3(4, 16, 32), 256, 0, stream>>>(qp, BpT1, db1, d1p);
  tail_k<<<dim3(9, 43, 32), 256, 0, stream>>>(d1p, BpT2, db2, Bpd3, db3, out);
}

// Round 11
// 279.532 us; speedup vs baseline: 1.4067x; 1.4067x over previous
//
#include <hip/hip_runtime.h>

typedef unsigned short u16;
typedef unsigned int u32;
typedef __attribute__((ext_vector_type(8))) short bf16x8;
typedef __attribute__((ext_vector_type(4))) float f32x4;

#define MFMA(a, b, c) __builtin_amdgcn_mfma_f32_16x16x32_bf16(a, b, c, 0, 0, 0)

__device__ __forceinline__ float b2f(u32 lo16) {
  union { u32 i; float f; } v; v.i = lo16 << 16; return v.f;
}
__device__ __forceinline__ u16 f2b(float f) {  // RNE (encoder path)
  union { float f; u32 i; } v; v.f = f;
  return (u16)((v.i + 0x7fffu + ((v.i >> 16) & 1u)) >> 16);
}
__device__ __forceinline__ u16 f2bt(float f) {  // truncate (decoder path, 1 op)
  union { float f; u32 i; } v; v.f = f;
  return (u16)(v.i >> 16);
}
__device__ __forceinline__ bf16x8 ld8(const u16* p) { return *(const bf16x8*)p; }

// ---------------------------------------------------------------------------
// prep: pack weights into MFMA fragment order, cnorm, zero loss.
// B-frag: [64 lanes][8]; elem j of lane l = W[k=8*(l>>4)+j][n=l&15].
// A-frag (BpT2 only): elem j of lane l = W[m=l&15][k=8*(l>>4)+j].
// ---------------------------------------------------------------------------
__global__ void prep_k(const float* __restrict__ ew1, const float* __restrict__ ew2,
                       const float* __restrict__ ew3, const float* __restrict__ dw1,
                       const float* __restrict__ dw2, const float* __restrict__ dw3,
                       const float* __restrict__ cb,
                       float* W1, u16* Bp2, u16* Bp3, u16* BpT1, u16* BpT2,
                       u16* Bpd3, u16* Bpvq, float* cnorm, float* loss) {
  int tid = blockIdx.x * blockDim.x + threadIdx.x;
  int nth = gridDim.x * blockDim.x;
  for (int i = tid; i < 1536; i += nth) {  // W1[3][4][4][32] f32 <- ew1[32][3][4][4]
    int oc = i & 31; int r = i >> 5; int kw = r & 3; r >>= 2; int kh = r & 3; int ic = r >> 2;
    W1[i] = ew1[((oc*3 + ic)*4 + kh)*4 + kw];
  }
  for (int i = tid; i < 32768; i += nth) {  // Bp2[t16][nt4][l][8] <- ew2[64][32][4][4]
    int j = i & 7, li = (i >> 3) & 63, nt = (i >> 9) & 3, t = i >> 11;
    int ic = 8*(li >> 4) + j, oc = 16*nt + (li & 15), kh = t >> 2, kw = t & 3;
    Bp2[i] = f2b(ew2[((oc*32 + ic)*4 + kh)*4 + kw]);
  }
  for (int i = tid; i < 36864; i += nth) {  // Bp3[t9][kc2][nt4][l][8] <- ew3[64][64][3][3]
    int j = i & 7, li = (i >> 3) & 63, nt = (i >> 9) & 3, kc = (i >> 11) & 1, t = i >> 12;
    int ic = 32*kc + 8*(li >> 4) + j, oc = 16*nt + (li & 15), kh = t / 3, kw = t % 3;
    Bp3[i] = f2b(ew3[((oc*64 + ic)*3 + kh)*3 + kw]);
  }
  for (int i = tid; i < 65536; i += nth) {  // BpT1[p4][t4][kc2][nt4][l][8] <- dw1[64][64][4][4]
    int j = i & 7, li = (i >> 3) & 63, nt = (i >> 9) & 3, kc = (i >> 11) & 1,
        t = (i >> 12) & 3, p = i >> 14;
    int a = p >> 1, b = p & 1;
    int ky = (1 - a) + 2*(t >> 1), kx = (1 - b) + 2*(t & 1);
    int ic = 32*kc + 8*(li >> 4) + j, oc = 16*nt + (li & 15);
    BpT1[i] = f2b(dw1[((ic*64 + oc)*4 + ky)*4 + kx]);
  }
  for (int i = tid; i < 32768; i += nth) {  // BpT2 A-frag [p4][t4][kc2][mt2][l][8]
    int j = i & 7, li = (i >> 3) & 63, mt = (i >> 9) & 1, kc = (i >> 10) & 1,
        t = (i >> 11) & 3, p = i >> 13;
    int a = p >> 1, b = p & 1;
    int ky = (1 - a) + 2*(t >> 1), kx = (1 - b) + 2*(t & 1);
    int oc = 16*mt + (li & 15);
    int ic = 32*kc + 8*(li >> 4) + j;
    BpT2[i] = f2b(dw2[((ic*32 + oc)*4 + ky)*4 + kx]);
  }
  for (int i = tid; i < 4608; i += nth) {  // Bpd3[t9][l][8] <- dw3[3][32][3][3], n pad 16
    int j = i & 7, li = (i >> 3) & 63, t = i >> 9;
    int n = li & 15, ic = 8*(li >> 4) + j, kh = t / 3, kw = t % 3;
    Bpd3[i] = (n < 3) ? f2b(dw3[((n*32 + ic)*3 + kh)*3 + kw]) : (u16)0;
  }
  for (int i = tid; i < 32768; i += nth) {  // Bpvq[kc2][nt32][l][8] <- cb[512][64]
    int j = i & 7, li = (i >> 3) & 63, nt = (i >> 9) & 31, kc = i >> 14;
    int d = 32*kc + 8*(li >> 4) + j, code = 16*nt + (li & 15);
    Bpvq[i] = f2b(cb[code*64 + d]);
  }
  for (int k = tid; k < 512; k += nth) {
    float s = 0.f;
    for (int d = 0; d < 64; ++d) { float c = cb[k*64 + d]; s += c*c; }
    cnorm[k] = s;
  }
  if (tid == 0) *loss = 0.f;
}

// ---------------------------------------------------------------------------
// conv1 (VALU): x f32 NCHW[32][3][256][256] -> h1 bf16 NHWC[32][128][128][32]
// ---------------------------------------------------------------------------
__global__ __launch_bounds__(256) void conv1_k(
    const float* __restrict__ x, const float* __restrict__ W1,
    const float* __restrict__ b1, u16* __restrict__ h1) {
  __shared__ float ins[3*18*36];
  int Tx = blockIdx.x, Ty = blockIdx.y, b = blockIdx.z;
  int tid = threadIdx.x;
  for (int i = tid; i < 3*18*36; i += 256) {
    int c = i % 36; int r = (i / 36) % 18; int ic = i / 648;
    int iy = 16*Ty - 1 + r, ix = 32*Tx - 2 + c;
    float v = 0.f;
    if ((unsigned)iy < 256u && (unsigned)ix < 256u)
      v = x[((size_t)(b*3 + ic)*256 + iy)*256 + ix];
    ins[i] = v;
  }
  __syncthreads();
  int posg = tid & 31, ocg = tid >> 5;
  int Y = posg >> 2, Xg = posg & 3;
  int oc0 = ocg * 4;
  float acc[4][4];
#pragma unroll
  for (int j = 0; j < 4; ++j) { float bv = b1[oc0 + j];
#pragma unroll
    for (int e = 0; e < 4; ++e) acc[j][e] = bv; }
  for (int ic = 0; ic < 3; ++ic)
#pragma unroll
    for (int kh = 0; kh < 4; ++kh) {
      const float* row = &ins[ic*648 + (2*Y + kh)*36 + 8*Xg];
      float win[12];
#pragma unroll
      for (int t = 0; t < 12; ++t) win[t] = row[t];
#pragma unroll
      for (int kw = 0; kw < 4; ++kw) {
        const float* wp = &W1[((ic*4 + kh)*4 + kw)*32 + oc0];
        float w0 = wp[0], w1 = wp[1], w2 = wp[2], w3 = wp[3];
#pragma unroll
        for (int e = 0; e < 4; ++e) {
          float v = win[2*e + kw + 1];
          acc[0][e] += w0*v; acc[1][e] += w1*v; acc[2][e] += w2*v; acc[3][e] += w3*v;
        }
      }
    }
  int oy = 8*Ty + Y;
  int oxb = 16*Tx + 4*Xg;
#pragma unroll
  for (int e = 0; e < 4; ++e) {
    u16* op = &h1[((size_t)(b*128 + oy)*128 + oxb + e)*32 + oc0];
#pragma unroll
    for (int j = 0; j < 4; ++j) op[j] = f2b(fmaxf(acc[j][e], 0.f));
  }
}

// ---------------------------------------------------------------------------
// conv2 (MFMA): h1 NHWC -> h2 bf16 NHWC[32][64][64][64], k4 s2 p1 relu.
// 8-row tile: wave w -> oy rows {w, w+4}.
// ---------------------------------------------------------------------------
__global__ __launch_bounds__(256) void conv2_k(
    const u16* __restrict__ h1, const u16* __restrict__ Bp2,
    const float* __restrict__ eb2, u16* __restrict__ h2) {
  __shared__ u16 lds[2448*8];  // [row18][c4][x34][8]
  int Tx = blockIdx.x, Ty = blockIdx.y, img = blockIdx.z;
  int tid = threadIdx.x;
  for (int i = tid; i < 2448; i += 256) {
    int c = i & 3; int x = (i >> 2) % 34; int row = (i >> 2) / 34;
    int iy = 16*Ty - 1 + row, ix = 32*Tx - 1 + x;
    f32x4 v = {0,0,0,0};
    if ((unsigned)iy < 128u && (unsigned)ix < 128u)
      v = *(const f32x4*)(h1 + (((size_t)(img*128 + iy)*128 + ix)*32 + c*8));
    *(f32x4*)(lds + ((row*4 + c)*34 + x)*8) = v;
  }
  __syncthreads();
  int w = tid >> 6, l = tid & 63, lg = l >> 4, lc = l & 15;
  f32x4 acc[2][4];
#pragma unroll
  for (int nt = 0; nt < 4; ++nt) {
    float bv = eb2[nt*16 + lc];
    acc[0][nt] = (f32x4){bv,bv,bv,bv}; acc[1][nt] = (f32x4){bv,bv,bv,bv};
  }
#pragma unroll
  for (int t = 0; t < 16; ++t) {
    int kh = t >> 2, kw = t & 3;
    bf16x8 a0 = ld8(lds + (((2*w + kh)*4 + lg)*34 + 2*lc + kw)*8);
    bf16x8 a1 = ld8(lds + (((2*(w+4) + kh)*4 + lg)*34 + 2*lc + kw)*8);
    const u16* bp = Bp2 + t*2048 + l*8;
    bf16x8 b0 = ld8(bp), b1 = ld8(bp + 512), b2v = ld8(bp + 1024), b3v = ld8(bp + 1536);
    acc[0][0] = MFMA(a0, b0, acc[0][0]); acc[0][1] = MFMA(a0, b1, acc[0][1]);
    acc[0][2] = MFMA(a0, b2v, acc[0][2]); acc[0][3] = MFMA(a0, b3v, acc[0][3]);
    acc[1][0] = MFMA(a1, b0, acc[1][0]); acc[1][1] = MFMA(a1, b1, acc[1][1]);
    acc[1][2] = MFMA(a1, b2v, acc[1][2]); acc[1][3] = MFMA(a1, b3v, acc[1][3]);
  }
#pragma unroll
  for (int m = 0; m < 2; ++m) {
    int oy = 8*Ty + w + m*4;
#pragma unroll
    for (int nt = 0; nt < 4; ++nt)
#pragma unroll
      for (int r = 0; r < 4; ++r) {
        int e = 4*lg + r;
        h2[((size_t)(img*64 + oy)*64 + 16*Tx + e)*64 + nt*16 + lc] =
            f2b(fmaxf(acc[m][nt][r], 0.f));
      }
  }
}

// ---------------------------------------------------------------------------
// conv3 enc (MFMA): h2 NHWC -> z bf16 NHWC[32][64][64][64], k3 s1 p1.
// ---------------------------------------------------------------------------
__global__ __launch_bounds__(256) void conv3e_k(
    const u16* __restrict__ h2, const u16* __restrict__ Bp3,
    const float* __restrict__ eb3, u16* __restrict__ z) {
  __shared__ u16 lds[1440*8];  // [row10][c8][x18][8]
  int Tx = blockIdx.x, Ty = blockIdx.y, img = blockIdx.z;
  int tid = threadIdx.x;
  for (int i = tid; i < 1440; i += 256) {
    int c = i & 7; int x = (i >> 3) % 18; int row = (i >> 3) / 18;
    int iy = 8*Ty - 1 + row, ix = 16*Tx - 1 + x;
    f32x4 v = {0,0,0,0};
    if ((unsigned)iy < 64u && (unsigned)ix < 64u)
      v = *(const f32x4*)(h2 + (((size_t)(img*64 + iy)*64 + ix)*64 + c*8));
    *(f32x4*)(lds + ((row*8 + c)*18 + x)*8) = v;
  }
  __syncthreads();
  int w = tid >> 6, l = tid & 63, lg = l >> 4, lc = l & 15;
  f32x4 acc[2][4];
#pragma unroll
  for (int nt = 0; nt < 4; ++nt) {
    float bv = eb3[nt*16 + lc];
    acc[0][nt] = (f32x4){bv,bv,bv,bv}; acc[1][nt] = (f32x4){bv,bv,bv,bv};
  }
#pragma unroll
  for (int t = 0; t < 9; ++t) {
    int kh = t / 3, kw = t % 3;
#pragma unroll
    for (int kc = 0; kc < 2; ++kc) {
      bf16x8 a0 = ld8(lds + (((w + kh)*8 + kc*4 + lg)*18 + lc + kw)*8);
      bf16x8 a1 = ld8(lds + (((w + 4 + kh)*8 + kc*4 + lg)*18 + lc + kw)*8);
      const u16* bp = Bp3 + (t*2 + kc)*2048 + l*8;
      bf16x8 b0 = ld8(bp), b1 = ld8(bp + 512), b2v = ld8(bp + 1024), b3v = ld8(bp + 1536);
      acc[0][0] = MFMA(a0, b0, acc[0][0]); acc[0][1] = MFMA(a0, b1, acc[0][1]);
      acc[0][2] = MFMA(a0, b2v, acc[0][2]); acc[0][3] = MFMA(a0, b3v, acc[0][3]);
      acc[1][0] = MFMA(a1, b0, acc[1][0]); acc[1][1] = MFMA(a1, b1, acc[1][1]);
      acc[1][2] = MFMA(a1, b2v, acc[1][2]); acc[1][3] = MFMA(a1, b3v, acc[1][3]);
    }
  }
#pragma unroll
  for (int m = 0; m < 2; ++m) {
    int oy = 8*Ty + w + m*4;
#pragma unroll
    for (int nt = 0; nt < 4; ++nt)
#pragma unroll
      for (int r = 0; r < 4; ++r) {
        int e = 4*lg + r;
        z[((size_t)(img*64 + oy)*64 + 16*Tx + e)*64 + nt*16 + lc] = f2b(acc[m][nt][r]);
      }
  }
}

// ---------------------------------------------------------------------------
// VQ (MFMA): z bf16 NHWC -> q bf16 NHWC + loss. 256 blocks x 8 iters
// (R6 config — measured ~20us faster than 1024x2).
// ---------------------------------------------------------------------------
__global__ __launch_bounds__(256) void vqm_k(
    const u16* __restrict__ z, const u16* __restrict__ Bpvq,
    const float* __restrict__ cnorm, const float* __restrict__ cbf,
    u16* __restrict__ q, float* __restrict__ loss) {
  __shared__ u16 cbl[32768];
  __shared__ float cnl[512];
  __shared__ int idxl[64];
  __shared__ float red[256];
  int tid = threadIdx.x;
  for (int i = tid; i < 4096; i += 256)
    *(f32x4*)(cbl + i*8) = *(const f32x4*)(Bpvq + i*8);
  for (int i = tid; i < 512; i += 256) cnl[i] = cnorm[i];
  __syncthreads();
  int w = tid >> 6, l = tid & 63, lg = l >> 4, lc = l & 15;
  int wglobal = blockIdx.x*4 + w;
  float lsum = 0.f;
  for (int it = 0; it < 8; ++it) {
    int mf = wglobal + it*1024;
    size_t P = (size_t)mf * 16;
    bf16x8 a0 = ld8(z + (P + lc)*64 + lg*8);
    bf16x8 a1 = ld8(z + (P + lc)*64 + 32 + lg*8);
    float best[4] = {1e30f, 1e30f, 1e30f, 1e30f};
    int bidx[4] = {0, 0, 0, 0};
    for (int nt = 0; nt < 32; ++nt) {
      f32x4 acc = {0,0,0,0};
      acc = MFMA(a0, ld8(cbl + (nt*64 + l)*8), acc);
      acc = MFMA(a1, ld8(cbl + ((32 + nt)*64 + l)*8), acc);
      float cn = cnl[nt*16 + lc];
      int code = nt*16 + lc;
#pragma unroll
      for (int r = 0; r < 4; ++r) {
        float dist = cn - 2.f*acc[r];
        if (dist < best[r]) { best[r] = dist; bidx[r] = code; }
      }
    }
#pragma unroll
    for (int r = 0; r < 4; ++r) {
      float b = best[r]; int bi = bidx[r];
      for (int m = 1; m < 16; m <<= 1) {
        float ob = __shfl_xor(b, m);
        int oi = __shfl_xor(bi, m);
        if (ob < b || (ob == b && oi < bi)) { b = ob; bi = oi; }
      }
      if (lc == 0) idxl[w*16 + lg*4 + r] = bi;
    }
    int m = lc, ch0 = lg*16;
    int id = idxl[w*16 + m];
    const float* crow = cbf + (size_t)id*64 + ch0;
    const u16* zp = z + (P + m)*64 + ch0;
    u32* qp = (u32*)(q + (P + m)*64 + ch0);
#pragma unroll
    for (int c = 0; c < 16; c += 2) {
      float c0 = crow[c], c1 = crow[c+1];
      float d0 = c0 - b2f(zp[c]), d1 = c1 - b2f(zp[c+1]);
      lsum += d0*d0 + d1*d1;
      qp[c >> 1] = (u32)f2bt(c0) | ((u32)f2bt(c1) << 16);
    }
  }
  red[tid] = lsum;
  __syncthreads();
  for (int s = 128; s > 0; s >>= 1) {
    if (tid < s) red[tid] += red[tid + s];
    __syncthreads();
  }
  if (tid == 0) atomicAdd(loss, red[0] * (1.25f / 8388608.f));
}

// ---------------------------------------------------------------------------
// convT1 (MFMA, parity): q NHWC -> d1 bf16 NHWC[32][128][128][64], k4 s2 p1 relu.
// ---------------------------------------------------------------------------
__global__ __launch_bounds__(256) void convt1_k(
    const u16* __restrict__ q, const u16* __restrict__ BpT1,
    const float* __restrict__ db1, u16* __restrict__ d1) {
  __shared__ u16 lds[864*8];  // [row6][c8][x18][8]
  int Tx = blockIdx.x, Ty = blockIdx.y, img = blockIdx.z;
  int X0 = 16*Tx, P0 = 4*Ty;
  int tid = threadIdx.x;
  for (int i = tid; i < 864; i += 256) {
    int c = i & 7; int x = (i >> 3) % 18; int row = (i >> 3) / 18;
    int iy = P0 - 1 + row, ix = X0 - 1 + x;
    f32x4 v = {0,0,0,0};
    if ((unsigned)iy < 64u && (unsigned)ix < 64u)
      v = *(const f32x4*)(q + (((size_t)(img*64 + iy)*64 + ix)*64 + c*8));
    *(f32x4*)(lds + ((row*8 + c)*18 + x)*8) = v;
  }
  __syncthreads();
  int w = tid >> 6, l = tid & 63, lg = l >> 4, lc = l & 15;
  int a = w & 1, bp_ = w >> 1;
  f32x4 acc[4][4];
#pragma unroll
  for (int nt = 0; nt < 4; ++nt) {
    float bv = db1[nt*16 + lc];
#pragma unroll
    for (int m = 0; m < 4; ++m) acc[m][nt] = (f32x4){bv,bv,bv,bv};
  }
  const u16* bbase = BpT1 + (size_t)(a*2 + bp_)*16384;
#pragma unroll
  for (int t = 0; t < 4; ++t) {
    int kyi = t >> 1, kxi = t & 1;
#pragma unroll
    for (int kc = 0; kc < 2; ++kc) {
      const u16* bp = bbase + (t*2 + kc)*2048 + l*8;
      bf16x8 b0 = ld8(bp), b1 = ld8(bp + 512), b2v = ld8(bp + 1024), b3v = ld8(bp + 1536);
      int xg = lc + bp_ - kxi + 1;
#pragma unroll
      for (int m = 0; m < 4; ++m) {
        int rowg = m + a - kyi + 1;
        bf16x8 av = ld8(lds + ((rowg*8 + kc*4 + lg)*18 + xg)*8);
        acc[m][0] = MFMA(av, b0, acc[m][0]);
        acc[m][1] = MFMA(av, b1, acc[m][1]);
        acc[m][2] = MFMA(av, b2v, acc[m][2]);
        acc[m][3] = MFMA(av, b3v, acc[m][3]);
      }
    }
  }
#pragma unroll
  for (int m = 0; m < 4; ++m) {
    int oy = 2*(P0 + m) + a;
#pragma unroll
    for (int nt = 0; nt < 4; ++nt)
#pragma unroll
      for (int r = 0; r < 4; ++r) {
        int e = 4*lg + r;
        int ox = 2*(X0 + e) + bp_;
        d1[((size_t)(img*128 + oy)*128 + ox)*64 + nt*16 + lc] =
            f2bt(fmaxf(acc[m][nt][r], 0.f));
      }
  }
}

// ---------------------------------------------------------------------------
// tail (MFMA): fused convT2+relu+conv3+sigmoid. Swapped-operand phase 1
// (A=weights M=oc, B=d1 N=x) -> packed b64 epilogue. d2q oc-row padded to 40
// u16 (80 B, 16B-aligned); phase-2 A-frag = 1 b128 read. rcp-sigmoid.
// ---------------------------------------------------------------------------
__global__ __launch_bounds__(256) void tail_k(
    const u16* __restrict__ d1, const u16* __restrict__ BpT2,
    const float* __restrict__ db2, const u16* __restrict__ Bpd3,
    const float* __restrict__ db3, float* __restrict__ out) {
  __shared__ u16 d1s[680*8];    // [row5][c8][x17][8]
  __shared__ u16 d2q[10240];    // [quad4][m4][x16][40]
  int Tx = blockIdx.x, Ty = blockIdx.y, img = blockIdx.z;
  int DX0 = 30*Tx - 1, DY0 = 6*Ty - 1;   // both odd
  int IYB = 3*Ty, IXB = 15*Tx;
  int tid = threadIdx.x;
  bool edge = (Tx == 0) | (Tx == 8) | (Ty == 0) | (Ty == 42);
  for (int i = tid; i < 680; i += 256) {
    int x = i % 17; int rc = i / 17; int c = rc & 7; int row = rc >> 3;
    int iy = IYB - 1 + row, ix = IXB - 1 + x;
    f32x4 v = {0,0,0,0};
    if ((unsigned)iy < 128u && (unsigned)ix < 128u)
      v = *(const f32x4*)(d1 + (((size_t)(img*128 + iy)*128 + ix)*64 + c*8));
    *(f32x4*)(d1s + ((row*8 + c)*17 + x)*8) = v;
  }
  __syncthreads();
  int w = tid >> 6, l = tid & 63, lg = l >> 4, lc = l & 15;
  {
    int a = w & 1, b = w >> 1;
    f32x4 acc[4][2];
#pragma unroll
    for (int mt = 0; mt < 2; ++mt) {
      f32x4 bv = *(const f32x4*)(db2 + 16*mt + 4*lg);
#pragma unroll
      for (int m = 0; m < 4; ++m) acc[m][mt] = bv;
    }
    const u16* bbase = BpT2 + (size_t)(a*2 + b)*8192;
#pragma unroll
    for (int kxi = 0; kxi < 2; ++kxi) {
      int xg = lc - kxi + 1;
#pragma unroll
      for (int kc = 0; kc < 2; ++kc) {
        bf16x8 av[5];
#pragma unroll
        for (int rr = 0; rr < 5; ++rr)
          av[rr] = ld8(d1s + ((rr*8 + kc*4 + lg)*17 + xg)*8);
#pragma unroll
        for (int kyi = 0; kyi < 2; ++kyi) {
          int t = kyi*2 + kxi;
          const u16* wb = bbase + (t*2 + kc)*1024 + l*8;
          bf16x8 w0 = ld8(wb), w1 = ld8(wb + 512);
#pragma unroll
          for (int m = 0; m < 4; ++m) {
            acc[m][0] = MFMA(w0, av[m + 1 - kyi], acc[m][0]);
            acc[m][1] = MFMA(w1, av[m + 1 - kyi], acc[m][1]);
          }
        }
      }
    }
    int base = (a*2 + b)*2560 + lc*40 + 4*lg;   // u16 units; + m*640 + mt*16
    if (!edge) {
#pragma unroll
      for (int m = 0; m < 4; ++m)
#pragma unroll
        for (int mt = 0; mt < 2; ++mt) {
          f32x4 v = acc[m][mt];
          u32 lo = (u32)f2bt(fmaxf(v[0], 0.f)) | ((u32)f2bt(fmaxf(v[1], 0.f)) << 16);
          u32 hi = (u32)f2bt(fmaxf(v[2], 0.f)) | ((u32)f2bt(fmaxf(v[3], 0.f)) << 16);
          *(uint2*)(d2q + base + m*640 + mt*16) = (uint2){lo, hi};
        }
    } else {
      int oxc = b ? DX0 : DX0 + 1;
      bool cm = (unsigned)(oxc + 2*lc) < 256u;
      int oyc = a ? DY0 : DY0 + 1;
#pragma unroll
      for (int m = 0; m < 4; ++m) {
        bool ok = ((unsigned)(oyc + 2*m) < 256u) && cm;
#pragma unroll
        for (int mt = 0; mt < 2; ++mt) {
          f32x4 v = acc[m][mt];
          u32 lo = 0, hi = 0;
          if (ok) {
            lo = (u32)f2bt(fmaxf(v[0], 0.f)) | ((u32)f2bt(fmaxf(v[1], 0.f)) << 16);
            hi = (u32)f2bt(fmaxf(v[2], 0.f)) | ((u32)f2bt(fmaxf(v[3], 0.f)) << 16);
          }
          *(uint2*)(d2q + base + m*640 + mt*16) = (uint2){lo, hi};
        }
      }
    }
  }
  __syncthreads();
  // phase 2: conv3x3 (32ic -> 3oc padded 16) + sigmoid on 6x30 interior
  bf16x8 bw[9];
#pragma unroll
  for (int t = 0; t < 9; ++t) bw[t] = ld8(Bpd3 + t*512 + l*8);
  float bv3 = (lc < 3) ? db3[lc] : 0.f;
#pragma unroll
  for (int i = 0; i < 3; ++i) {
    int u = w + 4*i;                 // 12 units, 3 per wave
    int yy = u >> 1, xf = u & 1;
    int gy = DY0 + 1 + yy;
    int cOff[3];
#pragma unroll
    for (int kw = 0; kw < 3; ++kw) {
      int lx = xf*16 + lc + kw; if (lx > 31) lx = 31;
      cOff[kw] = (1 - (lx & 1))*2560 + (lx >> 1)*40 + 8*lg;
    }
    f32x4 acc = {bv3, bv3, bv3, bv3};
#pragma unroll
    for (int kh = 0; kh < 3; ++kh) {
      int ly = yy + kh;
      int rOff = (1 - (ly & 1))*5120 + (ly >> 1)*640;
#pragma unroll
      for (int kw = 0; kw < 3; ++kw)
        acc = MFMA(ld8(d2q + rOff + cOff[kw]), bw[kh*3 + kw], acc);
    }
    if (lc < 3) {
      if (!edge) {
#pragma unroll
        for (int r = 0; r < 4; ++r) {
          int xi = xf*16 + 4*lg + r;
          if (xi < 30)
            out[((size_t)(img*3 + lc)*256 + gy)*256 + DX0 + 1 + xi] =
                __builtin_amdgcn_rcpf(1.f + __expf(-acc[r]));
        }
      } else if ((unsigned)gy < 256u) {
#pragma unroll
        for (int r = 0; r < 4; ++r) {
          int xi = xf*16 + 4*lg + r;
          int gx = DX0 + 1 + xi;
          if (xi < 30 && (unsigned)gx < 256u)
            out[((size_t)(img*3 + lc)*256 + gy)*256 + gx] =
                __builtin_amdgcn_rcpf(1.f + __expf(-acc[r]));
        }
      }
    }
  }
}

extern "C" void kernel_launch(void* const* d_in, const int* in_sizes, int n_in,
                              void* d_out, int out_size, void* d_ws, size_t ws_size,
                              hipStream_t stream) {
  const float* x   = (const float*)d_in[0];
  const float* ew1 = (const float*)d_in[1];
  const float* eb1 = (const float*)d_in[2];
  const float* ew2 = (const float*)d_in[3];
  const float* eb2 = (const float*)d_in[4];
  const float* ew3 = (const float*)d_in[5];
  const float* eb3 = (const float*)d_in[6];
  const float* cb  = (const float*)d_in[7];
  const float* dw1 = (const float*)d_in[8];
  const float* db1 = (const float*)d_in[9];
  const float* dw2 = (const float*)d_in[10];
  const float* db2 = (const float*)d_in[11];
  const float* dw3 = (const float*)d_in[12];
  const float* db3 = (const float*)d_in[13];
  float* out = (float*)d_out;

  // ws: h1/q [0,32M); d1 [16M,80M); h2 [32M,48M); z [48M,64M); weights @80M.
  char* ws = (char*)d_ws;
  const size_t MB = 1048576;
  u16* h1 = (u16*)ws;
  u16* q  = (u16*)ws;
  u16* d1 = (u16*)(ws + 16*MB);
  u16* h2 = (u16*)(ws + 32*MB);
  u16* z  = (u16*)(ws + 48*MB);
  char* wp = ws + 80*MB;
  float* W1   = (float*)wp;  wp += 6144;
  u16*  Bp2   = (u16*)wp;    wp += 65536;
  u16*  Bp3   = (u16*)wp;    wp += 73728;
  u16*  BpT1  = (u16*)wp;    wp += 131072;
  u16*  BpT2  = (u16*)wp;    wp += 65536;
  u16*  Bpd3  = (u16*)wp;    wp += 9216;
  u16*  Bpvq  = (u16*)wp;    wp += 65536;
  float* cnorm = (float*)wp; wp += 2048;
  float* loss = out + 6291456;

  prep_k<<<64, 256, 0, stream>>>(ew1, ew2, ew3, dw1, dw2, dw3, cb,
                                 W1, Bp2, Bp3, BpT1, BpT2, Bpd3, Bpvq, cnorm, loss);
  conv1_k<<<dim3(8, 16, 32), 256, 0, stream>>>(x, W1, eb1, h1);
  conv2_k<<<dim3(4, 8, 32), 256, 0, stream>>>(h1, Bp2, eb2, h2);
  conv3e_k<<<dim3(4, 8, 32), 256, 0, stream>>>(h2, Bp3, eb3, z);
  vqm_k<<<256, 256, 0, stream>>>(z, Bpvq, cnorm, cb, q, loss);
  convt1_k<<<dim3(4, 16, 32), 256, 0, stream>>>(q, BpT1, db1, d1);
  tail_k<<<dim3(9, 43, 32), 256, 0, stream>>>(d1, BpT2, db2, Bpd3, db3, out);
}

// Round 12
// 272.037 us; speedup vs baseline: 1.4455x; 1.0276x over previous
//
#include <hip/hip_runtime.h>

typedef unsigned short u16;
typedef unsigned int u32;
typedef __attribute__((ext_vector_type(8))) short bf16x8;
typedef __attribute__((ext_vector_type(4))) float f32x4;

#define MFMA(a, b, c) __builtin_amdgcn_mfma_f32_16x16x32_bf16(a, b, c, 0, 0, 0)

__device__ __forceinline__ float b2f(u32 lo16) {
  union { u32 i; float f; } v; v.i = lo16 << 16; return v.f;
}
__device__ __forceinline__ u16 f2b(float f) {  // RNE (encoder path)
  union { float f; u32 i; } v; v.f = f;
  return (u16)((v.i + 0x7fffu + ((v.i >> 16) & 1u)) >> 16);
}
__device__ __forceinline__ u16 f2bt(float f) {  // truncate (decoder path, 1 op)
  union { float f; u32 i; } v; v.f = f;
  return (u16)(v.i >> 16);
}
__device__ __forceinline__ bf16x8 ld8(const u16* p) { return *(const bf16x8*)p; }

// Async global->LDS, 16B per lane. LDS dest must be wave-uniform base + lane*16
// (our staging loops: dest = lds + i*16B, i = wavebase + lane). OOB lanes pass
// a zeroed 256B page as src (global addr is per-lane).
__device__ __forceinline__ void gload16(const void* g, void* l) {
  __builtin_amdgcn_global_load_lds(
      (const __attribute__((address_space(1))) u32*)g,
      (__attribute__((address_space(3))) u32*)l, 16, 0, 0);
}

// ---------------------------------------------------------------------------
// prep: pack weights into MFMA fragment order, cnorm, zero loss, zero page.
// B-frag: [64 lanes][8]; elem j of lane l = W[k=8*(l>>4)+j][n=l&15].
// A-frag (BpT2 only): elem j of lane l = W[m=l&15][k=8*(l>>4)+j].
// ---------------------------------------------------------------------------
__global__ void prep_k(const float* __restrict__ ew1, const float* __restrict__ ew2,
                       const float* __restrict__ ew3, const float* __restrict__ dw1,
                       const float* __restrict__ dw2, const float* __restrict__ dw3,
                       const float* __restrict__ cb,
                       float* W1, u16* Bp2, u16* Bp3, u16* BpT1, u16* BpT2,
                       u16* Bpd3, u16* Bpvq, float* cnorm, float* loss, u32* zpg) {
  int tid = blockIdx.x * blockDim.x + threadIdx.x;
  int nth = gridDim.x * blockDim.x;
  for (int i = tid; i < 1536; i += nth) {  // W1[3][4][4][32] f32 <- ew1[32][3][4][4]
    int oc = i & 31; int r = i >> 5; int kw = r & 3; r >>= 2; int kh = r & 3; int ic = r >> 2;
    W1[i] = ew1[((oc*3 + ic)*4 + kh)*4 + kw];
  }
  for (int i = tid; i < 32768; i += nth) {  // Bp2[t16][nt4][l][8] <- ew2[64][32][4][4]
    int j = i & 7, li = (i >> 3) & 63, nt = (i >> 9) & 3, t = i >> 11;
    int ic = 8*(li >> 4) + j, oc = 16*nt + (li & 15), kh = t >> 2, kw = t & 3;
    Bp2[i] = f2b(ew2[((oc*32 + ic)*4 + kh)*4 + kw]);
  }
  for (int i = tid; i < 36864; i += nth) {  // Bp3[t9][kc2][nt4][l][8] <- ew3[64][64][3][3]
    int j = i & 7, li = (i >> 3) & 63, nt = (i >> 9) & 3, kc = (i >> 11) & 1, t = i >> 12;
    int ic = 32*kc + 8*(li >> 4) + j, oc = 16*nt + (li & 15), kh = t / 3, kw = t % 3;
    Bp3[i] = f2b(ew3[((oc*64 + ic)*3 + kh)*3 + kw]);
  }
  for (int i = tid; i < 65536; i += nth) {  // BpT1[p4][t4][kc2][nt4][l][8] <- dw1[64][64][4][4]
    int j = i & 7, li = (i >> 3) & 63, nt = (i >> 9) & 3, kc = (i >> 11) & 1,
        t = (i >> 12) & 3, p = i >> 14;
    int a = p >> 1, b = p & 1;
    int ky = (1 - a) + 2*(t >> 1), kx = (1 - b) + 2*(t & 1);
    int ic = 32*kc + 8*(li >> 4) + j, oc = 16*nt + (li & 15);
    BpT1[i] = f2b(dw1[((ic*64 + oc)*4 + ky)*4 + kx]);
  }
  for (int i = tid; i < 32768; i += nth) {  // BpT2 A-frag [p4][t4][kc2][mt2][l][8]
    int j = i & 7, li = (i >> 3) & 63, mt = (i >> 9) & 1, kc = (i >> 10) & 1,
        t = (i >> 11) & 3, p = i >> 13;
    int a = p >> 1, b = p & 1;
    int ky = (1 - a) + 2*(t >> 1), kx = (1 - b) + 2*(t & 1);
    int oc = 16*mt + (li & 15);
    int ic = 32*kc + 8*(li >> 4) + j;
    BpT2[i] = f2b(dw2[((ic*32 + oc)*4 + ky)*4 + kx]);
  }
  for (int i = tid; i < 4608; i += nth) {  // Bpd3[t9][l][8] <- dw3[3][32][3][3], n pad 16
    int j = i & 7, li = (i >> 3) & 63, t = i >> 9;
    int n = li & 15, ic = 8*(li >> 4) + j, kh = t / 3, kw = t % 3;
    Bpd3[i] = (n < 3) ? f2b(dw3[((n*32 + ic)*3 + kh)*3 + kw]) : (u16)0;
  }
  for (int i = tid; i < 32768; i += nth) {  // Bpvq[kc2][nt32][l][8] <- cb[512][64]
    int j = i & 7, li = (i >> 3) & 63, nt = (i >> 9) & 31, kc = i >> 14;
    int d = 32*kc + 8*(li >> 4) + j, code = 16*nt + (li & 15);
    Bpvq[i] = f2b(cb[code*64 + d]);
  }
  for (int k = tid; k < 512; k += nth) {
    float s = 0.f;
    for (int d = 0; d < 64; ++d) { float c = cb[k*64 + d]; s += c*c; }
    cnorm[k] = s;
  }
  if (tid < 64) zpg[tid] = 0;   // 256B zero page for gload16 OOB clamp
  if (tid == 0) *loss = 0.f;
}

// ---------------------------------------------------------------------------
// conv1 (VALU): x f32 NCHW[32][3][256][256] -> h1 bf16 NHWC[32][128][128][32]
// ---------------------------------------------------------------------------
__global__ __launch_bounds__(256) void conv1_k(
    const float* __restrict__ x, const float* __restrict__ W1,
    const float* __restrict__ b1, u16* __restrict__ h1) {
  __shared__ float ins[3*18*36];
  int Tx = blockIdx.x, Ty = blockIdx.y, b = blockIdx.z;
  int tid = threadIdx.x;
  for (int i = tid; i < 3*18*36; i += 256) {
    int c = i % 36; int r = (i / 36) % 18; int ic = i / 648;
    int iy = 16*Ty - 1 + r, ix = 32*Tx - 2 + c;
    float v = 0.f;
    if ((unsigned)iy < 256u && (unsigned)ix < 256u)
      v = x[((size_t)(b*3 + ic)*256 + iy)*256 + ix];
    ins[i] = v;
  }
  __syncthreads();
  int posg = tid & 31, ocg = tid >> 5;
  int Y = posg >> 2, Xg = posg & 3;
  int oc0 = ocg * 4;
  float acc[4][4];
#pragma unroll
  for (int j = 0; j < 4; ++j) { float bv = b1[oc0 + j];
#pragma unroll
    for (int e = 0; e < 4; ++e) acc[j][e] = bv; }
  for (int ic = 0; ic < 3; ++ic)
#pragma unroll
    for (int kh = 0; kh < 4; ++kh) {
      const float* row = &ins[ic*648 + (2*Y + kh)*36 + 8*Xg];
      float win[12];
#pragma unroll
      for (int t = 0; t < 12; ++t) win[t] = row[t];
#pragma unroll
      for (int kw = 0; kw < 4; ++kw) {
        const float* wp = &W1[((ic*4 + kh)*4 + kw)*32 + oc0];
        float w0 = wp[0], w1 = wp[1], w2 = wp[2], w3 = wp[3];
#pragma unroll
        for (int e = 0; e < 4; ++e) {
          float v = win[2*e + kw + 1];
          acc[0][e] += w0*v; acc[1][e] += w1*v; acc[2][e] += w2*v; acc[3][e] += w3*v;
        }
      }
    }
  int oy = 8*Ty + Y;
  int oxb = 16*Tx + 4*Xg;
#pragma unroll
  for (int e = 0; e < 4; ++e) {
    u16* op = &h1[((size_t)(b*128 + oy)*128 + oxb + e)*32 + oc0];
#pragma unroll
    for (int j = 0; j < 4; ++j) op[j] = f2b(fmaxf(acc[j][e], 0.f));
  }
}

// ---------------------------------------------------------------------------
// conv2 (MFMA): h1 NHWC -> h2 bf16 NHWC[32][64][64][64], k4 s2 p1 relu.
// Staging via global_load_lds (16B), OOB clamped to zero page.
// ---------------------------------------------------------------------------
__global__ __launch_bounds__(256) void conv2_k(
    const u16* __restrict__ h1, const u16* __restrict__ Bp2,
    const float* __restrict__ eb2, u16* __restrict__ h2, const u32* zpg) {
  __shared__ u16 lds[2448*8];  // [row18][c4][x34][8]
  int Tx = blockIdx.x, Ty = blockIdx.y, img = blockIdx.z;
  int tid = threadIdx.x;
  for (int i = tid; i < 2448; i += 256) {
    int c = i & 3; int x = (i >> 2) % 34; int row = (i >> 2) / 34;
    int iy = 16*Ty - 1 + row, ix = 32*Tx - 1 + x;
    const void* src = ((unsigned)iy < 128u && (unsigned)ix < 128u)
        ? (const void*)(h1 + (((size_t)(img*128 + iy)*128 + ix)*32 + c*8))
        : (const void*)zpg;
    gload16(src, lds + i*8);
  }
  __syncthreads();
  int w = tid >> 6, l = tid & 63, lg = l >> 4, lc = l & 15;
  f32x4 acc[2][4];
#pragma unroll
  for (int nt = 0; nt < 4; ++nt) {
    float bv = eb2[nt*16 + lc];
    acc[0][nt] = (f32x4){bv,bv,bv,bv}; acc[1][nt] = (f32x4){bv,bv,bv,bv};
  }
#pragma unroll
  for (int t = 0; t < 16; ++t) {
    int kh = t >> 2, kw = t & 3;
    bf16x8 a0 = ld8(lds + (((2*w + kh)*4 + lg)*34 + 2*lc + kw)*8);
    bf16x8 a1 = ld8(lds + (((2*(w+4) + kh)*4 + lg)*34 + 2*lc + kw)*8);
    const u16* bp = Bp2 + t*2048 + l*8;
    bf16x8 b0 = ld8(bp), b1 = ld8(bp + 512), b2v = ld8(bp + 1024), b3v = ld8(bp + 1536);
    acc[0][0] = MFMA(a0, b0, acc[0][0]); acc[0][1] = MFMA(a0, b1, acc[0][1]);
    acc[0][2] = MFMA(a0, b2v, acc[0][2]); acc[0][3] = MFMA(a0, b3v, acc[0][3]);
    acc[1][0] = MFMA(a1, b0, acc[1][0]); acc[1][1] = MFMA(a1, b1, acc[1][1]);
    acc[1][2] = MFMA(a1, b2v, acc[1][2]); acc[1][3] = MFMA(a1, b3v, acc[1][3]);
  }
#pragma unroll
  for (int m = 0; m < 2; ++m) {
    int oy = 8*Ty + w + m*4;
#pragma unroll
    for (int nt = 0; nt < 4; ++nt)
#pragma unroll
      for (int r = 0; r < 4; ++r) {
        int e = 4*lg + r;
        h2[((size_t)(img*64 + oy)*64 + 16*Tx + e)*64 + nt*16 + lc] =
            f2b(fmaxf(acc[m][nt][r], 0.f));
      }
  }
}

// ---------------------------------------------------------------------------
// conv3 enc (MFMA): h2 NHWC -> z bf16 NHWC[32][64][64][64], k3 s1 p1.
// ---------------------------------------------------------------------------
__global__ __launch_bounds__(256) void conv3e_k(
    const u16* __restrict__ h2, const u16* __restrict__ Bp3,
    const float* __restrict__ eb3, u16* __restrict__ z, const u32* zpg) {
  __shared__ u16 lds[1440*8];  // [row10][c8][x18][8]
  int Tx = blockIdx.x, Ty = blockIdx.y, img = blockIdx.z;
  int tid = threadIdx.x;
  for (int i = tid; i < 1440; i += 256) {
    int c = i & 7; int x = (i >> 3) % 18; int row = (i >> 3) / 18;
    int iy = 8*Ty - 1 + row, ix = 16*Tx - 1 + x;
    const void* src = ((unsigned)iy < 64u && (unsigned)ix < 64u)
        ? (const void*)(h2 + (((size_t)(img*64 + iy)*64 + ix)*64 + c*8))
        : (const void*)zpg;
    gload16(src, lds + i*8);
  }
  __syncthreads();
  int w = tid >> 6, l = tid & 63, lg = l >> 4, lc = l & 15;
  f32x4 acc[2][4];
#pragma unroll
  for (int nt = 0; nt < 4; ++nt) {
    float bv = eb3[nt*16 + lc];
    acc[0][nt] = (f32x4){bv,bv,bv,bv}; acc[1][nt] = (f32x4){bv,bv,bv,bv};
  }
#pragma unroll
  for (int t = 0; t < 9; ++t) {
    int kh = t / 3, kw = t % 3;
#pragma unroll
    for (int kc = 0; kc < 2; ++kc) {
      bf16x8 a0 = ld8(lds + (((w + kh)*8 + kc*4 + lg)*18 + lc + kw)*8);
      bf16x8 a1 = ld8(lds + (((w + 4 + kh)*8 + kc*4 + lg)*18 + lc + kw)*8);
      const u16* bp = Bp3 + (t*2 + kc)*2048 + l*8;
      bf16x8 b0 = ld8(bp), b1 = ld8(bp + 512), b2v = ld8(bp + 1024), b3v = ld8(bp + 1536);
      acc[0][0] = MFMA(a0, b0, acc[0][0]); acc[0][1] = MFMA(a0, b1, acc[0][1]);
      acc[0][2] = MFMA(a0, b2v, acc[0][2]); acc[0][3] = MFMA(a0, b3v, acc[0][3]);
      acc[1][0] = MFMA(a1, b0, acc[1][0]); acc[1][1] = MFMA(a1, b1, acc[1][1]);
      acc[1][2] = MFMA(a1, b2v, acc[1][2]); acc[1][3] = MFMA(a1, b3v, acc[1][3]);
    }
  }
#pragma unroll
  for (int m = 0; m < 2; ++m) {
    int oy = 8*Ty + w + m*4;
#pragma unroll
    for (int nt = 0; nt < 4; ++nt)
#pragma unroll
      for (int r = 0; r < 4; ++r) {
        int e = 4*lg + r;
        z[((size_t)(img*64 + oy)*64 + 16*Tx + e)*64 + nt*16 + lc] = f2b(acc[m][nt][r]);
      }
  }
}

// ---------------------------------------------------------------------------
// VQ (MFMA): z bf16 NHWC -> q bf16 NHWC + loss. 256 blocks x 8 iters.
// ---------------------------------------------------------------------------
__global__ __launch_bounds__(256) void vqm_k(
    const u16* __restrict__ z, const u16* __restrict__ Bpvq,
    const float* __restrict__ cnorm, const float* __restrict__ cbf,
    u16* __restrict__ q, float* __restrict__ loss) {
  __shared__ u16 cbl[32768];
  __shared__ float cnl[512];
  __shared__ int idxl[64];
  __shared__ float red[256];
  int tid = threadIdx.x;
  for (int i = tid; i < 4096; i += 256)
    *(f32x4*)(cbl + i*8) = *(const f32x4*)(Bpvq + i*8);
  for (int i = tid; i < 512; i += 256) cnl[i] = cnorm[i];
  __syncthreads();
  int w = tid >> 6, l = tid & 63, lg = l >> 4, lc = l & 15;
  int wglobal = blockIdx.x*4 + w;
  float lsum = 0.f;
  for (int it = 0; it < 8; ++it) {
    int mf = wglobal + it*1024;
    size_t P = (size_t)mf * 16;
    bf16x8 a0 = ld8(z + (P + lc)*64 + lg*8);
    bf16x8 a1 = ld8(z + (P + lc)*64 + 32 + lg*8);
    float best[4] = {1e30f, 1e30f, 1e30f, 1e30f};
    int bidx[4] = {0, 0, 0, 0};
    for (int nt = 0; nt < 32; ++nt) {
      f32x4 acc = {0,0,0,0};
      acc = MFMA(a0, ld8(cbl + (nt*64 + l)*8), acc);
      acc = MFMA(a1, ld8(cbl + ((32 + nt)*64 + l)*8), acc);
      float cn = cnl[nt*16 + lc];
      int code = nt*16 + lc;
#pragma unroll
      for (int r = 0; r < 4; ++r) {
        float dist = cn - 2.f*acc[r];
        if (dist < best[r]) { best[r] = dist; bidx[r] = code; }
      }
    }
#pragma unroll
    for (int r = 0; r < 4; ++r) {
      float b = best[r]; int bi = bidx[r];
      for (int m = 1; m < 16; m <<= 1) {
        float ob = __shfl_xor(b, m);
        int oi = __shfl_xor(bi, m);
        if (ob < b || (ob == b && oi < bi)) { b = ob; bi = oi; }
      }
      if (lc == 0) idxl[w*16 + lg*4 + r] = bi;
    }
    int m = lc, ch0 = lg*16;
    int id = idxl[w*16 + m];
    const float* crow = cbf + (size_t)id*64 + ch0;
    const u16* zp = z + (P + m)*64 + ch0;
    u32* qp = (u32*)(q + (P + m)*64 + ch0);
#pragma unroll
    for (int c = 0; c < 16; c += 2) {
      float c0 = crow[c], c1 = crow[c+1];
      float d0 = c0 - b2f(zp[c]), d1 = c1 - b2f(zp[c+1]);
      lsum += d0*d0 + d1*d1;
      qp[c >> 1] = (u32)f2bt(c0) | ((u32)f2bt(c1) << 16);
    }
  }
  red[tid] = lsum;
  __syncthreads();
  for (int s = 128; s > 0; s >>= 1) {
    if (tid < s) red[tid] += red[tid + s];
    __syncthreads();
  }
  if (tid == 0) atomicAdd(loss, red[0] * (1.25f / 8388608.f));
}

// ---------------------------------------------------------------------------
// convT1 (MFMA, parity): q NHWC -> d1 bf16 NHWC[32][128][128][64], k4 s2 p1 relu.
// ---------------------------------------------------------------------------
__global__ __launch_bounds__(256) void convt1_k(
    const u16* __restrict__ q, const u16* __restrict__ BpT1,
    const float* __restrict__ db1, u16* __restrict__ d1, const u32* zpg) {
  __shared__ u16 lds[864*8];  // [row6][c8][x18][8]
  int Tx = blockIdx.x, Ty = blockIdx.y, img = blockIdx.z;
  int X0 = 16*Tx, P0 = 4*Ty;
  int tid = threadIdx.x;
  for (int i = tid; i < 864; i += 256) {
    int c = i & 7; int x = (i >> 3) % 18; int row = (i >> 3) / 18;
    int iy = P0 - 1 + row, ix = X0 - 1 + x;
    const void* src = ((unsigned)iy < 64u && (unsigned)ix < 64u)
        ? (const void*)(q + (((size_t)(img*64 + iy)*64 + ix)*64 + c*8))
        : (const void*)zpg;
    gload16(src, lds + i*8);
  }
  __syncthreads();
  int w = tid >> 6, l = tid & 63, lg = l >> 4, lc = l & 15;
  int a = w & 1, bp_ = w >> 1;
  f32x4 acc[4][4];
#pragma unroll
  for (int nt = 0; nt < 4; ++nt) {
    float bv = db1[nt*16 + lc];
#pragma unroll
    for (int m = 0; m < 4; ++m) acc[m][nt] = (f32x4){bv,bv,bv,bv};
  }
  const u16* bbase = BpT1 + (size_t)(a*2 + bp_)*16384;
#pragma unroll
  for (int t = 0; t < 4; ++t) {
    int kyi = t >> 1, kxi = t & 1;
#pragma unroll
    for (int kc = 0; kc < 2; ++kc) {
      const u16* bp = bbase + (t*2 + kc)*2048 + l*8;
      bf16x8 b0 = ld8(bp), b1 = ld8(bp + 512), b2v = ld8(bp + 1024), b3v = ld8(bp + 1536);
      int xg = lc + bp_ - kxi + 1;
#pragma unroll
      for (int m = 0; m < 4; ++m) {
        int rowg = m + a - kyi + 1;
        bf16x8 av = ld8(lds + ((rowg*8 + kc*4 + lg)*18 + xg)*8);
        acc[m][0] = MFMA(av, b0, acc[m][0]);
        acc[m][1] = MFMA(av, b1, acc[m][1]);
        acc[m][2] = MFMA(av, b2v, acc[m][2]);
        acc[m][3] = MFMA(av, b3v, acc[m][3]);
      }
    }
  }
#pragma unroll
  for (int m = 0; m < 4; ++m) {
    int oy = 2*(P0 + m) + a;
#pragma unroll
    for (int nt = 0; nt < 4; ++nt)
#pragma unroll
      for (int r = 0; r < 4; ++r) {
        int e = 4*lg + r;
        int ox = 2*(X0 + e) + bp_;
        d1[((size_t)(img*128 + oy)*128 + ox)*64 + nt*16 + lc] =
            f2bt(fmaxf(acc[m][nt][r], 0.f));
      }
  }
}

// ---------------------------------------------------------------------------
// tail (MFMA): fused convT2+relu+conv3+sigmoid. Swapped-operand phase 1
// (A=weights M=oc, B=d1 N=x) -> packed b64 epilogue. d2q oc-row padded to 40
// u16; phase-2 A-frag = 1 b128 read. rcp-sigmoid. gload_lds staging.
// ---------------------------------------------------------------------------
__global__ __launch_bounds__(256) void tail_k(
    const u16* __restrict__ d1, const u16* __restrict__ BpT2,
    const float* __restrict__ db2, const u16* __restrict__ Bpd3,
    const float* __restrict__ db3, float* __restrict__ out, const u32* zpg) {
  __shared__ u16 d1s[680*8];    // [row5][c8][x17][8]
  __shared__ u16 d2q[10240];    // [quad4][m4][x16][40]
  int Tx = blockIdx.x, Ty = blockIdx.y, img = blockIdx.z;
  int DX0 = 30*Tx - 1, DY0 = 6*Ty - 1;   // both odd
  int IYB = 3*Ty, IXB = 15*Tx;
  int tid = threadIdx.x;
  bool edge = (Tx == 0) | (Tx == 8) | (Ty == 0) | (Ty == 42);
  for (int i = tid; i < 680; i += 256) {
    int x = i % 17; int rc = i / 17; int c = rc & 7; int row = rc >> 3;
    int iy = IYB - 1 + row, ix = IXB - 1 + x;
    const void* src = ((unsigned)iy < 128u && (unsigned)ix < 128u)
        ? (const void*)(d1 + (((size_t)(img*128 + iy)*128 + ix)*64 + c*8))
        : (const void*)zpg;
    gload16(src, d1s + i*8);
  }
  __syncthreads();
  int w = tid >> 6, l = tid & 63, lg = l >> 4, lc = l & 15;
  {
    int a = w & 1, b = w >> 1;
    f32x4 acc[4][2];
#pragma unroll
    for (int mt = 0; mt < 2; ++mt) {
      f32x4 bv = *(const f32x4*)(db2 + 16*mt + 4*lg);
#pragma unroll
      for (int m = 0; m < 4; ++m) acc[m][mt] = bv;
    }
    const u16* bbase = BpT2 + (size_t)(a*2 + b)*8192;
#pragma unroll
    for (int kxi = 0; kxi < 2; ++kxi) {
      int xg = lc - kxi + 1;
#pragma unroll
      for (int kc = 0; kc < 2; ++kc) {
        bf16x8 av[5];
#pragma unroll
        for (int rr = 0; rr < 5; ++rr)
          av[rr] = ld8(d1s + ((rr*8 + kc*4 + lg)*17 + xg)*8);
#pragma unroll
        for (int kyi = 0; kyi < 2; ++kyi) {
          int t = kyi*2 + kxi;
          const u16* wb = bbase + (t*2 + kc)*1024 + l*8;
          bf16x8 w0 = ld8(wb), w1 = ld8(wb + 512);
#pragma unroll
          for (int m = 0; m < 4; ++m) {
            acc[m][0] = MFMA(w0, av[m + 1 - kyi], acc[m][0]);
            acc[m][1] = MFMA(w1, av[m + 1 - kyi], acc[m][1]);
          }
        }
      }
    }
    int base = (a*2 + b)*2560 + lc*40 + 4*lg;   // u16 units; + m*640 + mt*16
    if (!edge) {
#pragma unroll
      for (int m = 0; m < 4; ++m)
#pragma unroll
        for (int mt = 0; mt < 2; ++mt) {
          f32x4 v = acc[m][mt];
          u32 lo = (u32)f2bt(fmaxf(v[0], 0.f)) | ((u32)f2bt(fmaxf(v[1], 0.f)) << 16);
          u32 hi = (u32)f2bt(fmaxf(v[2], 0.f)) | ((u32)f2bt(fmaxf(v[3], 0.f)) << 16);
          *(uint2*)(d2q + base + m*640 + mt*16) = (uint2){lo, hi};
        }
    } else {
      int oxc = b ? DX0 : DX0 + 1;
      bool cm = (unsigned)(oxc + 2*lc) < 256u;
      int oyc = a ? DY0 : DY0 + 1;
#pragma unroll
      for (int m = 0; m < 4; ++m) {
        bool ok = ((unsigned)(oyc + 2*m) < 256u) && cm;
#pragma unroll
        for (int mt = 0; mt < 2; ++mt) {
          f32x4 v = acc[m][mt];
          u32 lo = 0, hi = 0;
          if (ok) {
            lo = (u32)f2bt(fmaxf(v[0], 0.f)) | ((u32)f2bt(fmaxf(v[1], 0.f)) << 16);
            hi = (u32)f2bt(fmaxf(v[2], 0.f)) | ((u32)f2bt(fmaxf(v[3], 0.f)) << 16);
          }
          *(uint2*)(d2q + base + m*640 + mt*16) = (uint2){lo, hi};
        }
      }
    }
  }
  __syncthreads();
  // phase 2: conv3x3 (32ic -> 3oc padded 16) + sigmoid on 6x30 interior
  bf16x8 bw[9];
#pragma unroll
  for (int t = 0; t < 9; ++t) bw[t] = ld8(Bpd3 + t*512 + l*8);
  float bv3 = (lc < 3) ? db3[lc] : 0.f;
#pragma unroll
  for (int i = 0; i < 3; ++i) {
    int u = w + 4*i;                 // 12 units, 3 per wave
    int yy = u >> 1, xf = u & 1;
    int gy = DY0 + 1 + yy;
    int cOff[3];
#pragma unroll
    for (int kw = 0; kw < 3; ++kw) {
      int lx = xf*16 + lc + kw; if (lx > 31) lx = 31;
      cOff[kw] = (1 - (lx & 1))*2560 + (lx >> 1)*40 + 8*lg;
    }
    f32x4 acc = {bv3, bv3, bv3, bv3};
#pragma unroll
    for (int kh = 0; kh < 3; ++kh) {
      int ly = yy + kh;
      int rOff = (1 - (ly & 1))*5120 + (ly >> 1)*640;
#pragma unroll
      for (int kw = 0; kw < 3; ++kw)
        acc = MFMA(ld8(d2q + rOff + cOff[kw]), bw[kh*3 + kw], acc);
    }
    if (lc < 3) {
      if (!edge) {
#pragma unroll
        for (int r = 0; r < 4; ++r) {
          int xi = xf*16 + 4*lg + r;
          if (xi < 30)
            out[((size_t)(img*3 + lc)*256 + gy)*256 + DX0 + 1 + xi] =
                __builtin_amdgcn_rcpf(1.f + __expf(-acc[r]));
        }
      } else if ((unsigned)gy < 256u) {
#pragma unroll
        for (int r = 0; r < 4; ++r) {
          int xi = xf*16 + 4*lg + r;
          int gx = DX0 + 1 + xi;
          if (xi < 30 && (unsigned)gx < 256u)
            out[((size_t)(img*3 + lc)*256 + gy)*256 + gx] =
                __builtin_amdgcn_rcpf(1.f + __expf(-acc[r]));
        }
      }
    }
  }
}

extern "C" void kernel_launch(void* const* d_in, const int* in_sizes, int n_in,
                              void* d_out, int out_size, void* d_ws, size_t ws_size,
                              hipStream_t stream) {
  const float* x   = (const float*)d_in[0];
  const float* ew1 = (const float*)d_in[1];
  const float* eb1 = (const float*)d_in[2];
  const float* ew2 = (const float*)d_in[3];
  const float* eb2 = (const float*)d_in[4];
  const float* ew3 = (const float*)d_in[5];
  const float* eb3 = (const float*)d_in[6];
  const float* cb  = (const float*)d_in[7];
  const float* dw1 = (const float*)d_in[8];
  const float* db1 = (const float*)d_in[9];
  const float* dw2 = (const float*)d_in[10];
  const float* db2 = (const float*)d_in[11];
  const float* dw3 = (const float*)d_in[12];
  const float* db3 = (const float*)d_in[13];
  float* out = (float*)d_out;

  // ws: h1/q [0,32M); d1 [16M,80M); h2 [32M,48M); z [48M,64M); weights @80M.
  char* ws = (char*)d_ws;
  const size_t MB = 1048576;
  u16* h1 = (u16*)ws;
  u16* q  = (u16*)ws;
  u16* d1 = (u16*)(ws + 16*MB);
  u16* h2 = (u16*)(ws + 32*MB);
  u16* z  = (u16*)(ws + 48*MB);
  char* wp = ws + 80*MB;
  float* W1   = (float*)wp;  wp += 6144;
  u16*  Bp2   = (u16*)wp;    wp += 65536;
  u16*  Bp3   = (u16*)wp;    wp += 73728;
  u16*  BpT1  = (u16*)wp;    wp += 131072;
  u16*  BpT2  = (u16*)wp;    wp += 65536;
  u16*  Bpd3  = (u16*)wp;    wp += 9216;
  u16*  Bpvq  = (u16*)wp;    wp += 65536;
  float* cnorm = (float*)wp; wp += 2048;
  u32*  zpg   = (u32*)wp;    wp += 256;
  float* loss = out + 6291456;

  prep_k<<<64, 256, 0, stream>>>(ew1, ew2, ew3, dw1, dw2, dw3, cb,
                                 W1, Bp2, Bp3, BpT1, BpT2, Bpd3, Bpvq, cnorm, loss, zpg);
  conv1_k<<<dim3(8, 16, 32), 256, 0, stream>>>(x, W1, eb1, h1);
  conv2_k<<<dim3(4, 8, 32), 256, 0, stream>>>(h1, Bp2, eb2, h2, zpg);
  conv3e_k<<<dim3(4, 8, 32), 256, 0, stream>>>(h2, Bp3, eb3, z, zpg);
  vqm_k<<<256, 256, 0, stream>>>(z, Bpvq, cnorm, cb, q, loss);
  convt1_k<<<dim3(4, 16, 32), 256, 0, stream>>>(q, BpT1, db1, d1, zpg);
  tail_k<<<dim3(9, 43, 32), 256, 0, stream>>>(d1, BpT2, db2, Bpd3, db3, out, zpg);
}